// Round 10
// baseline (179.899 us; speedup 1.0000x reference)
//
#include <hip/hip_runtime.h>
#include <math.h>

// (N,C,D,H,W)=(2,32,48,48,48), K=3, T=8. All fp32 in/out (verified R5).
// R20 = R19's 16B-entry gather at R18's occupancy. R19 post-mortem: per-wave
// path shrank 19% (81x13.5 vs 111x8 wave-time product) but 65KB LDS halved
// blocks/CU -> net loss. Fix: SINGLE tile buffer (16384 tok + 24352 tile =
// 40736 -> 4 blk/CU) with in-place restage between two barriers (R12: extra
// barriers ~free). VGPR discipline (R19 hit 156 via nld[48]+pqv[24]):
// split prefetch -- ch0-3 loaded at top, packed to 12 h2 regs post-gather;
// ch4-7 loaded mid-iter, packed at restage (waits covered by gather and
// token/MFMA phases respectively; peak carried ~36 regs = R18 level).
// B-fragments loaded at MFMA directly from L1/L2-resident 8KB table
// (removes 16 prefetch regs; ~200cy x 8 exposures ~ 1% of path).
#define NB   2
#define CH   32
#define DHW  (48*48*48)
#define TT   8
#define EPSF 1e-6f

#define TILE_N   1521            // 13*13*9 halo entries (1 entry = 8 ch fp16, 16B)
#define TILE_WSTR 1522           // entries (+1 zero pad)
#define TILE_BYTES (TILE_WSTR*16) // 24352
#define GROUPS   4               // 32 ch / 8 per group

// LDS layout (bytes): tokens [0,16384) = 256*64 ; tile [16384,40736)
// cbuf aliases [0,36864) = 256 rows * 36 floats (post-loop only)
#define TOK_OFF  0
#define TOK_STR  64              // 64B token rows, quadrant-XOR swizzled
#define TILE_OFF 16384
#define SMEM_SZ  (16384 + TILE_BYTES)   // 40736 -> 4 blocks/CU

// ws layout (float idx): Bt f16 [0,4096) floats (=8192 ushort), wf 4096, bf 4480, bm 4492
#define WS_BT_F 0
#define WS_WF   4096
#define WS_BF   4480
#define WS_BM   4492

typedef __attribute__((ext_vector_type(8))) short short8;
typedef __attribute__((ext_vector_type(8))) _Float16 half8;
typedef __attribute__((ext_vector_type(4))) float floatx4;
typedef __attribute__((ext_vector_type(2))) _Float16 h2;

struct __align__(16) q8v { h2 q[4]; };   // 8 packed channels (16B)

__device__ __forceinline__ h2 pkrtz(float a, float b) {
    return __builtin_bit_cast(h2, __builtin_amdgcn_cvt_pkrtz(a, b));
}
__device__ __forceinline__ unsigned pkrtz_u(float a, float b) {
    return __builtin_bit_cast(unsigned, __builtin_amdgcn_cvt_pkrtz(a, b));
}
__device__ __forceinline__ q8v ldq8(const char* p) {
    return __builtin_bit_cast(q8v, *(const half8*)p);
}
__device__ __forceinline__ void stq8(char* p, q8v v) {
    *(half8*)p = __builtin_bit_cast(half8, v);
}

__global__ __launch_bounds__(256) void prep_kernel(
        const float* __restrict__ w_field,
        const float* __restrict__ b_field,
        const float* __restrict__ gates,
        const float* __restrict__ w_mix,
        const float* __restrict__ b_mix,
        float* __restrict__ ws) {
    int i = blockIdx.x * 256 + threadIdx.x;    // grid 32*256 = 8192
    // Bt[o][k] f16 (RNE), k = c*8 + t, value = sigmoid(gates[t]) * w_mix[o, t*32+c]
    {
        int o = i >> 8, k = i & 255, c = k >> 3, t = k & 7;
        float sg = 1.0f / (1.0f + expf(-gates[t]));
        _Float16 hv = (_Float16)(sg * w_mix[o * 256 + t * 32 + c]);
        ((unsigned short*)(ws + WS_BT_F))[o * 256 + k] = __builtin_bit_cast(unsigned short, hv);
    }
    if (i < 384) { int c = i / 12, o = i - c * 12; ws[WS_WF + i] = w_field[o * 32 + c]; }
    if (i < 12)  ws[WS_BF + i] = b_field[i];
    if (i < 32)  ws[WS_BM + i] = b_mix[i];
}

__global__ __launch_bounds__(256) void geo_main(
        const float* __restrict__ x,
        const float* __restrict__ ws,
        float* __restrict__ out) {
    __shared__ __align__(16) char smem[SMEM_SZ];
    char* tokb  = smem + TOK_OFF;
    char* tileb = smem + TILE_OFF;             // single buffer of TILE_BYTES
    float* cbuf = (float*)smem;                // alias, post-loop only

    const int tid = threadIdx.x;
    // XCD-locality swizzle: chunk c = blockIdx&7 gets lin in [108c,108(c+1)).
    const int lin = (blockIdx.x & 7) * 108 + (blockIdx.x >> 3);
    const int bx = lin % 6, by = (lin / 6) % 6, bz = (lin / 36) % 12, n = lin / 432;
    const int lx = tid & 7, ly = (tid >> 3) & 7, lz = tid >> 6;
    const int w = bx * 8 + lx, h = by * 8 + ly, d = bz * 4 + lz;
    const int xlo = bx * 8 - 2, ylo = by * 8 - 2, zlo = bz * 4 - 2;
    const int lane = tid & 63, w64 = tid & 192;

    const float* xn = x + (size_t)n * CH * DHW;

    // ---- channel-invariant halo-load offsets ----
    int goff[6];
#pragma unroll
    for (int i = 0; i < 6; ++i) {
        int e  = tid + i * 256;
        int ee = (e < TILE_N) ? e : 0;
        int tz = ee / 169; int r0 = ee - tz * 169;
        int ty = r0 / 13;  int tx = r0 - ty * 13;
        int zg = min(max(zlo + tz, 0), 47);
        int yg = min(max(ylo + ty, 0), 47);
        int xg = min(max(xlo + tx, 0), 47);
        goff[i] = (zg * 48 + yg) * 48 + xg;
    }

    // ---- phase A: f[12] = w_field @ x(:,pos) + b_field ----
    const int pos = (d * 48 + h) * 48 + w;
    float f[12];
#pragma unroll
    for (int o = 0; o < 12; ++o) f[o] = ws[WS_BF + o];
    for (int c = 0; c < CH; ++c) {
        float xv = xn[c * DHW + pos];
        const float* wf = ws + WS_WF + c * 12;
#pragma unroll
        for (int o = 0; o < 12; ++o) f[o] = fmaf(wf[o], xv, f[o]);
    }

    // ---- per-voxel sample parameters (entry-index offsets) ----
    h2 fx2[6], fy2[6], fz2[6];
    int a00[6], a01[6], a10[6], a11[6];
    float uxk[3], uyk[3], uzk[3], irk[3], ir2k[3];
    const float cscale = 48.0f / (48.0f + EPSF);
#pragma unroll
    for (int k = 0; k < 3; ++k) {
        float vx = f[4*k], vy = f[4*k+1], vz = f[4*k+2], s = f[4*k+3];
        float inv = 1.0f / sqrtf(vx*vx + vy*vy + vz*vz + EPSF);
        float ux = vx * inv, uy = vy * inv, uz = vz * inv;
        float r  = 0.5f + 1.5f / (1.0f + expf(-s));
        uxk[k] = ux; uyk[k] = uy; uzk[k] = uz;
        float ir = 1.0f / (r + EPSF); irk[k] = ir; ir2k[k] = ir * ir;
#pragma unroll
        for (int sgn = 0; sgn < 2; ++sgn) {
            int   si = 2 * k + sgn;
            float sf = sgn ? -1.0f : 1.0f;
            float txr = (float)w + sf * r * ux * cscale;
            float tyr = (float)h + sf * r * uy * cscale;
            float tzr = (float)d + sf * r * uz * cscale;
            float cx = fabsf(txr + 0.5f); float ix = fminf(cx, 96.0f - cx) - 0.5f;
            float cy = fabsf(tyr + 0.5f); float iy = fminf(cy, 96.0f - cy) - 0.5f;
            float cz = fabsf(tzr + 0.5f); float iz = fminf(cz, 96.0f - cz) - 0.5f;
            float x0f = floorf(ix), y0f = floorf(iy), z0f = floorf(iz);
            float fx = ix - x0f, fy = iy - y0f, fz = iz - z0f;
            int x0 = min(max((int)x0f, 0), 47); int x1 = min(x0 + 1, 47);
            int y0 = min(max((int)y0f, 0), 47); int y1 = min(y0 + 1, 47);
            int z0 = min(max((int)z0f, 0), 47); int z1 = min(z0 + 1, 47);
            float fxe = (x1 == x0) ? 0.0f : fx;  // reference's clipped-x1 semantics
            _Float16 hx = (_Float16)fxe, hy = (_Float16)fy, hz = (_Float16)fz;
            fx2[si] = (h2){hx, hx}; fy2[si] = (h2){hy, hy}; fz2[si] = (h2){hz, hz};
            int lz0 = z0 - zlo, lz1 = z1 - zlo;
            int ly0 = y0 - ylo, ly1 = y1 - ylo;
            int lx0 = x0 - xlo;
            a00[si] = (lz0 * 13 + ly0) * 13 + lx0;
            a01[si] = (lz0 * 13 + ly1) * 13 + lx0;
            a10[si] = (lz1 * 13 + ly0) * 13 + lx0;
            a11[si] = (lz1 * 13 + ly1) * 13 + lx0;
        }
    }

    // ---- stage group 0 tile + zero pad entry ----
    if (tid == 0) {
        q8v z; z.q[0] = (h2){0,0}; z.q[1] = (h2){0,0}; z.q[2] = (h2){0,0}; z.q[3] = (h2){0,0};
        stq8(tileb + TILE_N * 16, z);
    }
    {
        float ld[48];
#pragma unroll
        for (int cg = 0; cg < 8; ++cg) {
            const float* xc = xn + cg * DHW;
#pragma unroll
            for (int i = 0; i < 6; ++i) ld[cg * 6 + i] = xc[goff[i]];
        }
#pragma unroll
        for (int i = 0; i < 6; ++i) {
            int e = tid + i * 256;
            if (e < TILE_N) {
                q8v vq;
                vq.q[0] = pkrtz(ld[i],      ld[6  + i]);
                vq.q[1] = pkrtz(ld[12 + i], ld[18 + i]);
                vq.q[2] = pkrtz(ld[24 + i], ld[30 + i]);
                vq.q[3] = pkrtz(ld[36 + i], ld[42 + i]);
                stq8(tileb + e * 16, vq);
            }
        }
    }
    __syncthreads();

    floatx4 acc[4][2];
#pragma unroll
    for (int mt = 0; mt < 4; ++mt)
#pragma unroll
        for (int nt = 0; nt < 2; ++nt) acc[mt][nt] = (floatx4){0.f, 0.f, 0.f, 0.f};

    const int self = ((lz + 2) * 13 + (ly + 2)) * 13 + (lx + 2);
    const unsigned short* bt = (const unsigned short*)(ws + WS_BT_F);
    const int tokq = (tid >> 3) & 3;           // token-quadrant swizzle key
    const int qm = lane >> 4, nlo = lane & 15;

    for (int g = 0; g < GROUPS; ++g) {
        // ---- prefetch batch A (next group's ch 0-3) ----
        float nldA[24];
        if (g < GROUPS - 1) {
            const float* xg = xn + (g + 1) * 8 * DHW;
#pragma unroll
            for (int cg = 0; cg < 4; ++cg) {
                const float* xc = xg + cg * DHW;
#pragma unroll
                for (int i = 0; i < 6; ++i) nldA[cg * 6 + i] = xc[goff[i]];
            }
        }
        // ---- packed trilinear: all 8 channels per site (16B entries) ----
        const char* tb = tileb;
        q8v s2 = ldq8(tb + self * 16);
        q8v vv[6];
#pragma unroll
        for (int si = 0; si < 6; ++si) {
            int b00 = a00[si], b01 = a01[si], b10 = a10[si], b11 = a11[si];
            q8v v000 = ldq8(tb + b00 * 16), v001 = ldq8(tb + b00 * 16 + 16);
            q8v v010 = ldq8(tb + b01 * 16), v011 = ldq8(tb + b01 * 16 + 16);
            q8v v100 = ldq8(tb + b10 * 16), v101 = ldq8(tb + b10 * 16 + 16);
            q8v v110 = ldq8(tb + b11 * 16), v111 = ldq8(tb + b11 * 16 + 16);
            h2 fx = fx2[si], fy = fy2[si], fz = fz2[si];
#pragma unroll
            for (int qd = 0; qd < 4; ++qd) {
                h2 c00 = v000.q[qd] + fx * (v001.q[qd] - v000.q[qd]);
                h2 c01 = v010.q[qd] + fx * (v011.q[qd] - v010.q[qd]);
                h2 c10 = v100.q[qd] + fx * (v101.q[qd] - v100.q[qd]);
                h2 c11 = v110.q[qd] + fx * (v111.q[qd] - v110.q[qd]);
                h2 c0  = c00 + fy * (c01 - c00);
                h2 c1  = c10 + fy * (c11 - c10);
                vv[si].q[qd] = c0 + fz * (c1 - c0);
            }
        }
        // ---- pack batch A (vmcnt covered by gather) + prefetch batch B ----
        h2 pqA[12];
        float nldB[24];
        if (g < GROUPS - 1) {
#pragma unroll
            for (int i = 0; i < 6; ++i) {
                pqA[i]     = pkrtz(nldA[i],      nldA[6  + i]);
                pqA[6 + i] = pkrtz(nldA[12 + i], nldA[18 + i]);
            }
            const float* xg = xn + ((g + 1) * 8 + 4) * DHW;
#pragma unroll
            for (int cg = 0; cg < 4; ++cg) {
                const float* xc = xg + cg * DHW;
#pragma unroll
                for (int i = 0; i < 6; ++i) nldB[cg * 6 + i] = xc[goff[i]];
            }
        }
        // ---- two wave-private sub-passes: tokens (4 ch) -> MFMA chunk ----
#pragma unroll
        for (int p = 0; p < 2; ++p) {
#pragma unroll
            for (int j = 0; j < 4; ++j) {
                const int ce = p * 4 + j;      // channel element 0..7 (compile-time)
                float xv = (ce & 1) ? (float)s2.q[ce >> 1].y : (float)s2.q[ce >> 1].x;
                float val[6];
#pragma unroll
                for (int si = 0; si < 6; ++si)
                    val[si] = (ce & 1) ? (float)vv[si].q[ce >> 1].y : (float)vv[si].q[ce >> 1].x;
                float t1, t2, t3, gx, gy, gz, l;
                {
                    float sp, sm, d1;
                    sp = val[0]; sm = val[1]; t1 = 0.5f * (sp + sm);
                    d1 = 0.5f * (sp - sm) * irk[0];
                    gx = uxk[0] * d1; gy = uyk[0] * d1; gz = uzk[0] * d1;
                    l  = (sp + sm - 2.0f * xv) * ir2k[0];
                    sp = val[2]; sm = val[3]; t2 = 0.5f * (sp + sm);
                    d1 = 0.5f * (sp - sm) * irk[1];
                    gx = fmaf(uxk[1], d1, gx); gy = fmaf(uyk[1], d1, gy); gz = fmaf(uzk[1], d1, gz);
                    l  = fmaf(sp + sm - 2.0f * xv, ir2k[1], l);
                    sp = val[4]; sm = val[5]; t3 = 0.5f * (sp + sm);
                    d1 = 0.5f * (sp - sm) * irk[2];
                    gx = fmaf(uxk[2], d1, gx); gy = fmaf(uyk[2], d1, gy); gz = fmaf(uzk[2], d1, gz);
                    l  = fmaf(sp + sm - 2.0f * xv, ir2k[2], l);
                }
                uint4 tw;
                tw.x = pkrtz_u(xv, t1);
                tw.y = pkrtz_u(t2, t3);
                tw.z = pkrtz_u(gx, gy);
                tw.w = pkrtz_u(gz, l * (1.0f / 3.0f));
                int qe = j ^ tokq;             // bank-conflict-free token write
                *(uint4*)(tokb + tid * TOK_STR + qe * 16) = tw;
            }
            // MFMA chunk cc = 2g+p (k = cc*32 .. cc*32+31), fp16.
            // Tokens wave-private: in-order per-wave LDS suffices, no barrier.
            // B fragments from L1/L2-resident 8KB table (no prefetch regs).
            {
                const int cc = 2 * g + p;
                half8 hb0 = __builtin_bit_cast(half8,
                            *(const short8*)(bt + (nlo * 256 + cc * 32 + qm * 8)));
                half8 hb1 = __builtin_bit_cast(half8,
                            *(const short8*)(bt + ((nlo + 16) * 256 + cc * 32 + qm * 8)));
#pragma unroll
                for (int mt = 0; mt < 4; ++mt) {
                    int row = w64 + mt * 16 + nlo;
                    int qe  = qm ^ ((row >> 3) & 3);
                    half8 a = __builtin_bit_cast(half8,
                              *(const short8*)(tokb + row * TOK_STR + qe * 16));
                    acc[mt][0] = __builtin_amdgcn_mfma_f32_16x16x32_f16(a, hb0, acc[mt][0], 0, 0, 0);
                    acc[mt][1] = __builtin_amdgcn_mfma_f32_16x16x32_f16(a, hb1, acc[mt][1], 0, 0, 0);
                }
            }
        }
        __syncthreads();   // all tile reads for group g complete

        // ---- in-place restage: pack batch B (vmcnt covered by tokens+MFMA) ----
        if (g < GROUPS - 1) {
#pragma unroll
            for (int i = 0; i < 6; ++i) {
                int e = tid + i * 256;
                if (e < TILE_N) {
                    q8v vq;
                    vq.q[0] = pqA[i];
                    vq.q[1] = pqA[6 + i];
                    vq.q[2] = pkrtz(nldB[i],      nldB[6  + i]);
                    vq.q[3] = pkrtz(nldB[12 + i], nldB[18 + i]);
                    stq8(tileb + e * 16, vq);
                }
            }
        }
        __syncthreads();   // restaged tile visible
    }

    // ---- C writeback via LDS (col-swizzled, conflict-free) ----
    {
#pragma unroll
        for (int mt = 0; mt < 4; ++mt)
#pragma unroll
            for (int nt = 0; nt < 2; ++nt)
#pragma unroll
                for (int r = 0; r < 4; ++r) {
                    int vr = w64 + mt * 16 + qm * 4 + r;
                    int col = nt * 16 + nlo;
                    cbuf[vr * 36 + (col ^ (vr & 31))] = acc[mt][nt][r];
                }
    }
    __syncthreads();

    // ---- epilogue: out = x + delta + b_mix (coalesced, nontemporal) ----
    const float* dr = cbuf + tid * 36;
    float* on = out + (size_t)n * CH * DHW;
#pragma unroll
    for (int o = 0; o < 32; ++o)
        __builtin_nontemporal_store(
            xn[o * DHW + pos] + dr[o ^ (tid & 31)] + ws[WS_BM + o],
            on + o * DHW + pos);
}

extern "C" void kernel_launch(void* const* d_in, const int* in_sizes, int n_in,
                              void* d_out, int out_size, void* d_ws, size_t ws_size,
                              hipStream_t stream) {
    const float *x = (const float*)d_in[0], *w_field = (const float*)d_in[1],
                *b_field = (const float*)d_in[2], *gates = (const float*)d_in[3],
                *w_mix = (const float*)d_in[4], *b_mix = (const float*)d_in[5];
    for (int i = 0; i < n_in; ++i) {
        switch (in_sizes[i]) {
            case NB * CH * DHW: x       = (const float*)d_in[i]; break;
            case 12 * CH:       w_field = (const float*)d_in[i]; break;
            case 12:            b_field = (const float*)d_in[i]; break;
            case TT:            gates   = (const float*)d_in[i]; break;
            case CH * TT * CH:  w_mix   = (const float*)d_in[i]; break;
            case CH:            b_mix   = (const float*)d_in[i]; break;
            default: break;
        }
    }
    float* ws = (float*)d_ws;
    prep_kernel<<<32, 256, 0, stream>>>(w_field, b_field, gates, w_mix, b_mix, ws);
    geo_main<<<864, 256, 0, stream>>>(x, ws, (float*)d_out);
}

// Round 11
// 155.340 us; speedup vs baseline: 1.1581x; 1.1581x over previous
//
#include <hip/hip_runtime.h>
#include <math.h>

// (N,C,D,H,W)=(2,32,48,48,48), K=3, T=8. All fp32 in/out (verified R5).
// R21 = R18 (best 154.57, geo 81us) + packed-f16 token assembly (R16's
// concept minus its killer). R16 failed ONLY because launch_bounds(256,4)
// pinned VGPR to 64 -> spills; its packed token math passed correctness.
// R19/R20 post-mortem: 16B-entry structure can't fit {LDS<=40KB, VGPR<=128}
// -> abandoned. Here: R18 structure untouched (8B entries, GROUPS=8,
// stage-early pqv pipeline, single barrier), token math done as h2 pairs
// (~33 pk-ops + 8 v_perm vs ~64 ops incl. 12 cvts) -- saves ~480 VALU
// instrs/thread (~15% of the dominant 34% VALU pipe). h2 constants
// (hux/huy/huz/hir/hq, 15 regs) REPLACE f32 ones (uxk..ir2k, 15 regs):
// net-zero live state. No launch_bounds pin.
#define NB   2
#define CH   32
#define DHW  (48*48*48)
#define TT   8
#define EPSF 1e-6f

#define TILE_N   1521            // 13*13*9 halo entries (1 entry = 4 ch fp16, 8B)
#define TILE_WSTR 1522           // entries per buffer (+1 zero pad)
#define GROUPS   8               // 32 ch / 4 per group

// LDS layout (bytes): tokens [0,16384) = 256*64 ; tile 2 bufs [16384,40736)
// cbuf aliases [0,36864) = 256 rows * 36 floats (post-loop only)
#define TOK_OFF  0
#define TOK_STR  64              // 64B tokens, quadrant-XOR swizzled
#define TILE_OFF 16384
#define SMEM_SZ  40736

// ws layout (float idx): Bt f16 [0,4096) floats (=8192 ushort), wf 4096, bf 4480, bm 4492
#define WS_BT_F 0
#define WS_WF   4096
#define WS_BF   4480
#define WS_BM   4492

typedef __attribute__((ext_vector_type(8))) short short8;
typedef __attribute__((ext_vector_type(8))) _Float16 half8;
typedef __attribute__((ext_vector_type(4))) float floatx4;
typedef __attribute__((ext_vector_type(2))) _Float16 h2;

struct __align__(8) q4 { h2 lo, hi; };   // 4 packed channels (8B, b64-aligned)

__device__ __forceinline__ h2 pkrtz(float a, float b) {
    return __builtin_bit_cast(h2, __builtin_amdgcn_cvt_pkrtz(a, b));
}
__device__ __forceinline__ h2 dup2(float v) {
    _Float16 h = (_Float16)v; return (h2){h, h};
}
__device__ __forceinline__ unsigned h2u(h2 v) {
    return __builtin_bit_cast(unsigned, v);
}

__global__ __launch_bounds__(256) void prep_kernel(
        const float* __restrict__ w_field,
        const float* __restrict__ b_field,
        const float* __restrict__ gates,
        const float* __restrict__ w_mix,
        const float* __restrict__ b_mix,
        float* __restrict__ ws) {
    int i = blockIdx.x * 256 + threadIdx.x;    // grid 32*256 = 8192
    // Bt[o][k] f16 (RNE), k = c*8 + t, value = sigmoid(gates[t]) * w_mix[o, t*32+c]
    {
        int o = i >> 8, k = i & 255, c = k >> 3, t = k & 7;
        float sg = 1.0f / (1.0f + expf(-gates[t]));
        _Float16 hv = (_Float16)(sg * w_mix[o * 256 + t * 32 + c]);
        ((unsigned short*)(ws + WS_BT_F))[o * 256 + k] = __builtin_bit_cast(unsigned short, hv);
    }
    if (i < 384) { int c = i / 12, o = i - c * 12; ws[WS_WF + i] = w_field[o * 32 + c]; }
    if (i < 12)  ws[WS_BF + i] = b_field[i];
    if (i < 32)  ws[WS_BM + i] = b_mix[i];
}

__global__ __launch_bounds__(256) void geo_main(
        const float* __restrict__ x,
        const float* __restrict__ ws,
        float* __restrict__ out) {
    __shared__ __align__(16) char smem[SMEM_SZ];
    char* tokb  = smem + TOK_OFF;
    q4*   tileq = (q4*)(smem + TILE_OFF);      // entry-indexed, 2 buffers of TILE_WSTR
    float* cbuf = (float*)smem;                // alias, post-loop only

    const int tid = threadIdx.x;
    // XCD-locality swizzle: chunk c = blockIdx&7 gets lin in [108c,108(c+1)).
    const int lin = (blockIdx.x & 7) * 108 + (blockIdx.x >> 3);
    const int bx = lin % 6, by = (lin / 6) % 6, bz = (lin / 36) % 12, n = lin / 432;
    const int lx = tid & 7, ly = (tid >> 3) & 7, lz = tid >> 6;
    const int w = bx * 8 + lx, h = by * 8 + ly, d = bz * 4 + lz;
    const int xlo = bx * 8 - 2, ylo = by * 8 - 2, zlo = bz * 4 - 2;
    const int lane = tid & 63, w64 = tid & 192;

    const float* xn = x + (size_t)n * CH * DHW;

    // ---- channel-invariant halo-load offsets ----
    int goff[6];
#pragma unroll
    for (int i = 0; i < 6; ++i) {
        int e  = tid + i * 256;
        int ee = (e < TILE_N) ? e : 0;
        int tz = ee / 169; int r0 = ee - tz * 169;
        int ty = r0 / 13;  int tx = r0 - ty * 13;
        int zg = min(max(zlo + tz, 0), 47);
        int yg = min(max(ylo + ty, 0), 47);
        int xg = min(max(xlo + tx, 0), 47);
        goff[i] = (zg * 48 + yg) * 48 + xg;
    }

    // ---- phase A: f[12] = w_field @ x(:,pos) + b_field ----
    const int pos = (d * 48 + h) * 48 + w;
    float f[12];
#pragma unroll
    for (int o = 0; o < 12; ++o) f[o] = ws[WS_BF + o];
    for (int c = 0; c < CH; ++c) {
        float xv = xn[c * DHW + pos];
        const float* wf = ws + WS_WF + c * 12;
#pragma unroll
        for (int o = 0; o < 12; ++o) f[o] = fmaf(wf[o], xv, f[o]);
    }

    // ---- per-voxel sample parameters ----
    h2 fx2[6], fy2[6], fz2[6];
    int a00[6], a01[6], a10[6], a11[6];
    h2 hux[3], huy[3], huz[3], hir[3], hq[3];  // packed token constants
    const float cscale = 48.0f / (48.0f + EPSF);
#pragma unroll
    for (int k = 0; k < 3; ++k) {
        float vx = f[4*k], vy = f[4*k+1], vz = f[4*k+2], s = f[4*k+3];
        float inv = 1.0f / sqrtf(vx*vx + vy*vy + vz*vz + EPSF);
        float ux = vx * inv, uy = vy * inv, uz = vz * inv;
        float r  = 0.5f + 1.5f / (1.0f + expf(-s));
        float ir = 1.0f / (r + EPSF);
        hux[k] = dup2(ux); huy[k] = dup2(uy); huz[k] = dup2(uz);
        hir[k] = dup2(0.5f * ir);
        hq[k]  = dup2(ir * ir * (1.0f / 3.0f));
#pragma unroll
        for (int sgn = 0; sgn < 2; ++sgn) {
            int   si = 2 * k + sgn;
            float sf = sgn ? -1.0f : 1.0f;
            float txr = (float)w + sf * r * ux * cscale;
            float tyr = (float)h + sf * r * uy * cscale;
            float tzr = (float)d + sf * r * uz * cscale;
            float cx = fabsf(txr + 0.5f); float ix = fminf(cx, 96.0f - cx) - 0.5f;
            float cy = fabsf(tyr + 0.5f); float iy = fminf(cy, 96.0f - cy) - 0.5f;
            float cz = fabsf(tzr + 0.5f); float iz = fminf(cz, 96.0f - cz) - 0.5f;
            float x0f = floorf(ix), y0f = floorf(iy), z0f = floorf(iz);
            float fx = ix - x0f, fy = iy - y0f, fz = iz - z0f;
            int x0 = min(max((int)x0f, 0), 47); int x1 = min(x0 + 1, 47);
            int y0 = min(max((int)y0f, 0), 47); int y1 = min(y0 + 1, 47);
            int z0 = min(max((int)z0f, 0), 47); int z1 = min(z0 + 1, 47);
            float fxe = (x1 == x0) ? 0.0f : fx;  // reference's clipped-x1 semantics
            _Float16 hx = (_Float16)fxe, hy = (_Float16)fy, hz = (_Float16)fz;
            fx2[si] = (h2){hx, hx}; fy2[si] = (h2){hy, hy}; fz2[si] = (h2){hz, hz};
            int lz0 = z0 - zlo, lz1 = z1 - zlo;
            int ly0 = y0 - ylo, ly1 = y1 - ylo;
            int lx0 = x0 - xlo;
            a00[si] = (lz0 * 13 + ly0) * 13 + lx0;
            a01[si] = (lz0 * 13 + ly1) * 13 + lx0;
            a10[si] = (lz1 * 13 + ly0) * 13 + lx0;
            a11[si] = (lz1 * 13 + ly1) * 13 + lx0;
        }
    }

    // ---- stage group 0 tile into buffer 0 + zero both pad entries ----
    if (tid == 0) {
        q4 z; z.lo = (h2){0, 0}; z.hi = (h2){0, 0};
        tileq[TILE_N] = z; tileq[TILE_WSTR + TILE_N] = z;
    }
    {
        float ld[24];
#pragma unroll
        for (int cg = 0; cg < 4; ++cg) {
            const float* xc = xn + cg * DHW;
#pragma unroll
            for (int i = 0; i < 6; ++i) ld[cg * 6 + i] = xc[goff[i]];
        }
#pragma unroll
        for (int i = 0; i < 6; ++i) {
            int e = tid + i * 256;
            if (e < TILE_N) {
                q4 vq; vq.lo = pkrtz(ld[i], ld[6 + i]); vq.hi = pkrtz(ld[12 + i], ld[18 + i]);
                tileq[e] = vq;
            }
        }
    }

    // ---- preload group 1 into pqv registers (staged at top of iter 0) ----
    q4 pqv[6];
    {
        float l2[24];
#pragma unroll
        for (int cg = 0; cg < 4; ++cg) {
            const float* xc = xn + (4 + cg) * DHW;
#pragma unroll
            for (int i = 0; i < 6; ++i) l2[cg * 6 + i] = xc[goff[i]];
        }
#pragma unroll
        for (int i = 0; i < 6; ++i) {
            pqv[i].lo = pkrtz(l2[i], l2[6 + i]);
            pqv[i].hi = pkrtz(l2[12 + i], l2[18 + i]);
        }
    }
    __syncthreads();

    floatx4 acc[4][2];
#pragma unroll
    for (int mt = 0; mt < 4; ++mt)
#pragma unroll
        for (int nt = 0; nt < 2; ++nt) acc[mt][nt] = (floatx4){0.f, 0.f, 0.f, 0.f};

    const int self = ((lz + 2) * 13 + (ly + 2)) * 13 + (lx + 2);
    const unsigned short* bt = (const unsigned short*)(ws + WS_BT_F);
    const int tokq = (tid >> 3) & 3;           // token-quadrant swizzle key
    const int qm = lane >> 4, nlo = lane & 15;
    const h2 HHALF = dup2(0.5f);

    // B-fragment rolling prefetch (hidden under trilinear compute)
    short8 bc0 = *(const short8*)(bt + (nlo * 256 + qm * 8));
    short8 bc1 = *(const short8*)(bt + ((nlo + 16) * 256 + qm * 8));

    for (int g = 0; g < GROUPS; ++g) {
        const int rb = (g & 1);                // read buffer (group g)
        const int wb = rb ^ 1;                 // write buffer (group g+1)
        // ---- stage-early: write group g+1's tile from pqv (reg->LDS, no wait) ----
        if (g < GROUPS - 1) {
#pragma unroll
            for (int i = 0; i < 6; ++i) {
                int e = tid + i * 256;
                if (e < TILE_N) tileq[wb * TILE_WSTR + e] = pqv[i];
            }
        }
        // ---- issue global prefetch for group g+2 ----
        float nld[24];
        if (g < GROUPS - 2) {
            const float* xg = xn + (g + 2) * 4 * DHW;
#pragma unroll
            for (int cg = 0; cg < 4; ++cg) {
                const float* xc = xg + cg * DHW;
#pragma unroll
                for (int i = 0; i < 6; ++i) nld[cg * 6 + i] = xc[goff[i]];
            }
        }
        short8 bn0 = bc0, bn1 = bc1;
        if (g < GROUPS - 1) {
            bn0 = *(const short8*)(bt + (nlo * 256 + (g + 1) * 32 + qm * 8));
            bn1 = *(const short8*)(bt + ((nlo + 16) * 256 + (g + 1) * 32 + qm * 8));
        }
        // ---- packed trilinear: all 4 channels per site (8B entries) ----
        const q4* tb = tileq + rb * TILE_WSTR;
        q4 sc = tb[self];
        q4 vv[6];
#pragma unroll
        for (int si = 0; si < 6; ++si) {
            int b00 = a00[si], b01 = a01[si], b10 = a10[si], b11 = a11[si];
            q4 v000 = tb[b00], v001 = tb[b00 + 1];
            q4 v010 = tb[b01], v011 = tb[b01 + 1];
            q4 v100 = tb[b10], v101 = tb[b10 + 1];
            q4 v110 = tb[b11], v111 = tb[b11 + 1];
            h2 fx = fx2[si], fy = fy2[si], fz = fz2[si];
            h2 c00l = v000.lo + fx * (v001.lo - v000.lo);
            h2 c00h = v000.hi + fx * (v001.hi - v000.hi);
            h2 c01l = v010.lo + fx * (v011.lo - v010.lo);
            h2 c01h = v010.hi + fx * (v011.hi - v010.hi);
            h2 c10l = v100.lo + fx * (v101.lo - v100.lo);
            h2 c10h = v100.hi + fx * (v101.hi - v100.hi);
            h2 c11l = v110.lo + fx * (v111.lo - v110.lo);
            h2 c11h = v110.hi + fx * (v111.hi - v110.hi);
            h2 c0l = c00l + fy * (c01l - c00l);
            h2 c0h = c00h + fy * (c01h - c00h);
            h2 c1l = c10l + fy * (c11l - c10l);
            h2 c1h = c10h + fy * (c11h - c10h);
            vv[si].lo = c0l + fz * (c1l - c0l);
            vv[si].hi = c0h + fz * (c1h - c0h);
        }
        // ---- token assembly: packed f16 math on channel pairs ----
#pragma unroll
        for (int pr = 0; pr < 2; ++pr) {
            h2 X  = pr ? sc.hi : sc.lo;
            h2 V0 = pr ? vv[0].hi : vv[0].lo;
            h2 V1 = pr ? vv[1].hi : vv[1].lo;
            h2 V2 = pr ? vv[2].hi : vv[2].lo;
            h2 V3 = pr ? vv[3].hi : vv[3].lo;
            h2 V4 = pr ? vv[4].hi : vv[4].lo;
            h2 V5 = pr ? vv[5].hi : vv[5].lo;
            h2 xv2 = X + X;
            h2 s0 = V0 + V1, dm0 = V0 - V1;
            h2 t1 = HHALF * s0;
            h2 d0 = dm0 * hir[0];
            h2 gx = d0 * hux[0], gy = d0 * huy[0], gz = d0 * huz[0];
            h2 l  = (s0 - xv2) * hq[0];
            h2 s1 = V2 + V3, dm1 = V2 - V3;
            h2 t2 = HHALF * s1;
            h2 d1 = dm1 * hir[1];
            gx = d1 * hux[1] + gx; gy = d1 * huy[1] + gy; gz = d1 * huz[1] + gz;
            l  = (s1 - xv2) * hq[1] + l;
            h2 s2v = V4 + V5, dm2 = V4 - V5;
            h2 t3 = HHALF * s2v;
            h2 d2 = dm2 * hir[2];
            gx = d2 * hux[2] + gx; gy = d2 * huy[2] + gy; gz = d2 * huz[2] + gz;
            l  = (s2v - xv2) * hq[2] + l;
            // word packing: .x channel takes lo16s, .y channel hi16s
            uint4 twa, twb;
            twa.x = __builtin_amdgcn_perm(h2u(t1), h2u(X),  0x05040100u);
            twa.y = __builtin_amdgcn_perm(h2u(t3), h2u(t2), 0x05040100u);
            twa.z = __builtin_amdgcn_perm(h2u(gy), h2u(gx), 0x05040100u);
            twa.w = __builtin_amdgcn_perm(h2u(l),  h2u(gz), 0x05040100u);
            twb.x = __builtin_amdgcn_perm(h2u(t1), h2u(X),  0x07060302u);
            twb.y = __builtin_amdgcn_perm(h2u(t3), h2u(t2), 0x07060302u);
            twb.z = __builtin_amdgcn_perm(h2u(gy), h2u(gx), 0x07060302u);
            twb.w = __builtin_amdgcn_perm(h2u(l),  h2u(gz), 0x07060302u);
            int qa = (2 * pr)     ^ tokq;
            int qb = (2 * pr + 1) ^ tokq;
            *(uint4*)(tokb + tid * TOK_STR + qa * 16) = twa;
            *(uint4*)(tokb + tid * TOK_STR + qb * 16) = twb;
        }
        // ---- MFMA: K-chunk g (k = g*32 .. g*32+31), fp16 ----
        // Tokens are wave-private: in-order per-wave LDS suffices, no barrier.
        {
            half8 hb0 = __builtin_bit_cast(half8, bc0);
            half8 hb1 = __builtin_bit_cast(half8, bc1);
#pragma unroll
            for (int mt = 0; mt < 4; ++mt) {
                int row = w64 + mt * 16 + nlo;
                int qe  = qm ^ ((row >> 3) & 3);
                half8 a = __builtin_bit_cast(half8,
                          *(const short8*)(tokb + row * TOK_STR + qe * 16));
                acc[mt][0] = __builtin_amdgcn_mfma_f32_16x16x32_f16(a, hb0, acc[mt][0], 0, 0, 0);
                acc[mt][1] = __builtin_amdgcn_mfma_f32_16x16x32_f16(a, hb1, acc[mt][1], 0, 0, 0);
            }
        }
        bc0 = bn0; bc1 = bn1;

        // ---- pack g+2's loads into pqv for next iteration's stage ----
        if (g < GROUPS - 2) {
#pragma unroll
            for (int i = 0; i < 6; ++i) {
                pqv[i].lo = pkrtz(nld[i], nld[6 + i]);
                pqv[i].hi = pkrtz(nld[12 + i], nld[18 + i]);
            }
        }
        __syncthreads();   // single rendezvous: buf[wb] staged, buf[rb] reads done
    }

    // ---- C writeback via LDS (col-swizzled, conflict-free) ----
    {
#pragma unroll
        for (int mt = 0; mt < 4; ++mt)
#pragma unroll
            for (int nt = 0; nt < 2; ++nt)
#pragma unroll
                for (int r = 0; r < 4; ++r) {
                    int vr = w64 + mt * 16 + qm * 4 + r;
                    int col = nt * 16 + nlo;
                    cbuf[vr * 36 + (col ^ (vr & 31))] = acc[mt][nt][r];
                }
    }
    __syncthreads();

    // ---- epilogue: out = x + delta + b_mix (coalesced, nontemporal) ----
    const float* dr = cbuf + tid * 36;
    float* on = out + (size_t)n * CH * DHW;
#pragma unroll
    for (int o = 0; o < 32; ++o)
        __builtin_nontemporal_store(
            xn[o * DHW + pos] + dr[o ^ (tid & 31)] + ws[WS_BM + o],
            on + o * DHW + pos);
}

extern "C" void kernel_launch(void* const* d_in, const int* in_sizes, int n_in,
                              void* d_out, int out_size, void* d_ws, size_t ws_size,
                              hipStream_t stream) {
    const float *x = (const float*)d_in[0], *w_field = (const float*)d_in[1],
                *b_field = (const float*)d_in[2], *gates = (const float*)d_in[3],
                *w_mix = (const float*)d_in[4], *b_mix = (const float*)d_in[5];
    for (int i = 0; i < n_in; ++i) {
        switch (in_sizes[i]) {
            case NB * CH * DHW: x       = (const float*)d_in[i]; break;
            case 12 * CH:       w_field = (const float*)d_in[i]; break;
            case 12:            b_field = (const float*)d_in[i]; break;
            case TT:            gates   = (const float*)d_in[i]; break;
            case CH * TT * CH:  w_mix   = (const float*)d_in[i]; break;
            case CH:            b_mix   = (const float*)d_in[i]; break;
            default: break;
        }
    }
    float* ws = (float*)d_ws;
    prep_kernel<<<32, 256, 0, stream>>>(w_field, b_field, gates, w_mix, b_mix, ws);
    geo_main<<<864, 256, 0, stream>>>(x, ws, (float*)d_out);
}

// Round 12
// 147.018 us; speedup vs baseline: 1.2237x; 1.0566x over previous
//
#include <hip/hip_runtime.h>
#include <math.h>

// (N,C,D,H,W)=(2,32,48,48,48), K=3, T=8. All fp32 in/out (verified R5).
// R22 = R21 + XOR bank-swizzle on the halo tile to kill GATHER conflicts.
// Evidence: R21 cut VALU 34->28.8% with zero time change (not VALU-bound);
// SQ_LDS_BANK_CONFLICT 1.2e7 = 47k cy/CU = 24% of elapsed, ~all in the
// trilinear gather (8.9 extra cy per gather read). With 8B entries bank-pair
// = e mod 16; jitter deltas of 16 (dy=+1,dx=+3 etc.) pile whole rows on one
// bank-pair. Fix: slot = (e & ~15) | ((e ^ (e>>4)) & 15) -- permutes entries
// within each 16-entry block, so de=16k pairs land on distinct bank-pairs.
// All gather addrs (incl +1 x-neighbors) precomputed swizzled (+24 VGPR,
// 96 -> ~120 <= 128). Tile slots 1536/buffer: LDS = 16384 + 2*12288 = 40960
// (still 4 blk/CU); pad slots [1520,1534] pre-zeroed in both buffers so
// swizzled reads of entry 1521 return 0 (reference's clipped semantics).
#define NB   2
#define CH   32
#define DHW  (48*48*48)
#define TT   8
#define EPSF 1e-6f

#define TILE_N     1521          // real halo entries 13*13*9 (1 entry = 4 ch fp16, 8B)
#define TILE_SLOTS 1536          // rounded to 16-entry blocks for the swizzle
#define TILE_BYTES (TILE_SLOTS*8) // 12288 per buffer
#define GROUPS   8               // 32 ch / 4 per group

// LDS layout (bytes): tokens [0,16384) = 256*64 ; tile 2 bufs [16384,40960)
// cbuf aliases [0,36864) = 256 rows * 36 floats (post-loop only)
#define TOK_OFF  0
#define TOK_STR  64              // 64B tokens, quadrant-XOR swizzled
#define TILE_OFF 16384
#define SMEM_SZ  (16384 + 2*TILE_BYTES)   // 40960 -> 4 blocks/CU exactly

// ws layout (float idx): Bt f16 [0,4096) floats (=8192 ushort), wf 4096, bf 4480, bm 4492
#define WS_BT_F 0
#define WS_WF   4096
#define WS_BF   4480
#define WS_BM   4492

typedef __attribute__((ext_vector_type(8))) short short8;
typedef __attribute__((ext_vector_type(8))) _Float16 half8;
typedef __attribute__((ext_vector_type(4))) float floatx4;
typedef __attribute__((ext_vector_type(2))) _Float16 h2;

struct __align__(8) q4 { h2 lo, hi; };   // 4 packed channels (8B, b64-aligned)

__device__ __forceinline__ h2 pkrtz(float a, float b) {
    return __builtin_bit_cast(h2, __builtin_amdgcn_cvt_pkrtz(a, b));
}
__device__ __forceinline__ h2 dup2(float v) {
    _Float16 h = (_Float16)v; return (h2){h, h};
}
__device__ __forceinline__ unsigned h2u(h2 v) {
    return __builtin_bit_cast(unsigned, v);
}
// bank-conflict swizzle: permute entry within its aligned 16-entry block
__device__ __forceinline__ int swze(int e) {
    return (e & ~15) | ((e ^ (e >> 4)) & 15);
}

__global__ __launch_bounds__(256) void prep_kernel(
        const float* __restrict__ w_field,
        const float* __restrict__ b_field,
        const float* __restrict__ gates,
        const float* __restrict__ w_mix,
        const float* __restrict__ b_mix,
        float* __restrict__ ws) {
    int i = blockIdx.x * 256 + threadIdx.x;    // grid 32*256 = 8192
    // Bt[o][k] f16 (RNE), k = c*8 + t, value = sigmoid(gates[t]) * w_mix[o, t*32+c]
    {
        int o = i >> 8, k = i & 255, c = k >> 3, t = k & 7;
        float sg = 1.0f / (1.0f + expf(-gates[t]));
        _Float16 hv = (_Float16)(sg * w_mix[o * 256 + t * 32 + c]);
        ((unsigned short*)(ws + WS_BT_F))[o * 256 + k] = __builtin_bit_cast(unsigned short, hv);
    }
    if (i < 384) { int c = i / 12, o = i - c * 12; ws[WS_WF + i] = w_field[o * 32 + c]; }
    if (i < 12)  ws[WS_BF + i] = b_field[i];
    if (i < 32)  ws[WS_BM + i] = b_mix[i];
}

__global__ __launch_bounds__(256) void geo_main(
        const float* __restrict__ x,
        const float* __restrict__ ws,
        float* __restrict__ out) {
    __shared__ __align__(16) char smem[SMEM_SZ];
    char* tokb  = smem + TOK_OFF;
    char* tbuf  = smem + TILE_OFF;             // 2 buffers of TILE_BYTES
    float* cbuf = (float*)smem;                // alias, post-loop only

    const int tid = threadIdx.x;
    // XCD-locality swizzle: chunk c = blockIdx&7 gets lin in [108c,108(c+1)).
    const int lin = (blockIdx.x & 7) * 108 + (blockIdx.x >> 3);
    const int bx = lin % 6, by = (lin / 6) % 6, bz = (lin / 36) % 12, n = lin / 432;
    const int lx = tid & 7, ly = (tid >> 3) & 7, lz = tid >> 6;
    const int w = bx * 8 + lx, h = by * 8 + ly, d = bz * 4 + lz;
    const int xlo = bx * 8 - 2, ylo = by * 8 - 2, zlo = bz * 4 - 2;
    const int lane = tid & 63, w64 = tid & 192;

    const float* xn = x + (size_t)n * CH * DHW;

    // ---- channel-invariant halo-load offsets ----
    int goff[6];
#pragma unroll
    for (int i = 0; i < 6; ++i) {
        int e  = tid + i * 256;
        int ee = (e < TILE_N) ? e : 0;
        int tz = ee / 169; int r0 = ee - tz * 169;
        int ty = r0 / 13;  int tx = r0 - ty * 13;
        int zg = min(max(zlo + tz, 0), 47);
        int yg = min(max(ylo + ty, 0), 47);
        int xg = min(max(xlo + tx, 0), 47);
        goff[i] = (zg * 48 + yg) * 48 + xg;
    }

    // ---- phase A: f[12] = w_field @ x(:,pos) + b_field ----
    const int pos = (d * 48 + h) * 48 + w;
    float f[12];
#pragma unroll
    for (int o = 0; o < 12; ++o) f[o] = ws[WS_BF + o];
    for (int c = 0; c < CH; ++c) {
        float xv = xn[c * DHW + pos];
        const float* wf = ws + WS_WF + c * 12;
#pragma unroll
        for (int o = 0; o < 12; ++o) f[o] = fmaf(wf[o], xv, f[o]);
    }

    // ---- per-voxel sample parameters (swizzled byte offsets) ----
    h2 fx2[6], fy2[6], fz2[6];
    int a00s[6], a00p[6], a01s[6], a01p[6];
    int a10s[6], a10p[6], a11s[6], a11p[6];
    h2 hux[3], huy[3], huz[3], hir[3], hq[3];  // packed token constants
    const float cscale = 48.0f / (48.0f + EPSF);
#pragma unroll
    for (int k = 0; k < 3; ++k) {
        float vx = f[4*k], vy = f[4*k+1], vz = f[4*k+2], s = f[4*k+3];
        float inv = 1.0f / sqrtf(vx*vx + vy*vy + vz*vz + EPSF);
        float ux = vx * inv, uy = vy * inv, uz = vz * inv;
        float r  = 0.5f + 1.5f / (1.0f + expf(-s));
        float ir = 1.0f / (r + EPSF);
        hux[k] = dup2(ux); huy[k] = dup2(uy); huz[k] = dup2(uz);
        hir[k] = dup2(0.5f * ir);
        hq[k]  = dup2(ir * ir * (1.0f / 3.0f));
#pragma unroll
        for (int sgn = 0; sgn < 2; ++sgn) {
            int   si = 2 * k + sgn;
            float sf = sgn ? -1.0f : 1.0f;
            float txr = (float)w + sf * r * ux * cscale;
            float tyr = (float)h + sf * r * uy * cscale;
            float tzr = (float)d + sf * r * uz * cscale;
            float cx = fabsf(txr + 0.5f); float ix = fminf(cx, 96.0f - cx) - 0.5f;
            float cy = fabsf(tyr + 0.5f); float iy = fminf(cy, 96.0f - cy) - 0.5f;
            float cz = fabsf(tzr + 0.5f); float iz = fminf(cz, 96.0f - cz) - 0.5f;
            float x0f = floorf(ix), y0f = floorf(iy), z0f = floorf(iz);
            float fx = ix - x0f, fy = iy - y0f, fz = iz - z0f;
            int x0 = min(max((int)x0f, 0), 47); int x1 = min(x0 + 1, 47);
            int y0 = min(max((int)y0f, 0), 47); int y1 = min(y0 + 1, 47);
            int z0 = min(max((int)z0f, 0), 47); int z1 = min(z0 + 1, 47);
            float fxe = (x1 == x0) ? 0.0f : fx;  // reference's clipped-x1 semantics
            _Float16 hx = (_Float16)fxe, hy = (_Float16)fy, hz = (_Float16)fz;
            fx2[si] = (h2){hx, hx}; fy2[si] = (h2){hy, hy}; fz2[si] = (h2){hz, hz};
            int lz0 = z0 - zlo, lz1 = z1 - zlo;
            int ly0 = y0 - ylo, ly1 = y1 - ylo;
            int lx0 = x0 - xlo;
            int i00 = (lz0 * 13 + ly0) * 13 + lx0;
            int i01 = (lz0 * 13 + ly1) * 13 + lx0;
            int i10 = (lz1 * 13 + ly0) * 13 + lx0;
            int i11 = (lz1 * 13 + ly1) * 13 + lx0;
            a00s[si] = swze(i00) * 8; a00p[si] = swze(i00 + 1) * 8;
            a01s[si] = swze(i01) * 8; a01p[si] = swze(i01 + 1) * 8;
            a10s[si] = swze(i10) * 8; a10p[si] = swze(i10 + 1) * 8;
            a11s[si] = swze(i11) * 8; a11p[si] = swze(i11 + 1) * 8;
        }
    }

    // ---- zero pad slots [1520,1534] in both buffers (swz(1520)=1535 is real) ----
    if (tid < 30) {
        int b = tid / 15, j = tid % 15;
        *(q4*)(tbuf + b * TILE_BYTES + (1520 + j) * 8) = q4{(h2){0,0}, (h2){0,0}};
    }
    // ---- stage group 0 tile into buffer 0 (swizzled slots) ----
    {
        float ld[24];
#pragma unroll
        for (int cg = 0; cg < 4; ++cg) {
            const float* xc = xn + cg * DHW;
#pragma unroll
            for (int i = 0; i < 6; ++i) ld[cg * 6 + i] = xc[goff[i]];
        }
#pragma unroll
        for (int i = 0; i < 6; ++i) {
            int e = tid + i * 256;
            if (e < TILE_N) {
                q4 vq; vq.lo = pkrtz(ld[i], ld[6 + i]); vq.hi = pkrtz(ld[12 + i], ld[18 + i]);
                *(q4*)(tbuf + swze(e) * 8) = vq;
            }
        }
    }

    // ---- preload group 1 into pqv registers (staged at top of iter 0) ----
    q4 pqv[6];
    {
        float l2[24];
#pragma unroll
        for (int cg = 0; cg < 4; ++cg) {
            const float* xc = xn + (4 + cg) * DHW;
#pragma unroll
            for (int i = 0; i < 6; ++i) l2[cg * 6 + i] = xc[goff[i]];
        }
#pragma unroll
        for (int i = 0; i < 6; ++i) {
            pqv[i].lo = pkrtz(l2[i], l2[6 + i]);
            pqv[i].hi = pkrtz(l2[12 + i], l2[18 + i]);
        }
    }
    __syncthreads();

    floatx4 acc[4][2];
#pragma unroll
    for (int mt = 0; mt < 4; ++mt)
#pragma unroll
        for (int nt = 0; nt < 2; ++nt) acc[mt][nt] = (floatx4){0.f, 0.f, 0.f, 0.f};

    const int selfB = swze(((lz + 2) * 13 + (ly + 2)) * 13 + (lx + 2)) * 8;
    const unsigned short* bt = (const unsigned short*)(ws + WS_BT_F);
    const int tokq = (tid >> 3) & 3;           // token-quadrant swizzle key
    const int qm = lane >> 4, nlo = lane & 15;
    const h2 HHALF = dup2(0.5f);

    // B-fragment rolling prefetch (hidden under trilinear compute)
    short8 bc0 = *(const short8*)(bt + (nlo * 256 + qm * 8));
    short8 bc1 = *(const short8*)(bt + ((nlo + 16) * 256 + qm * 8));

    for (int g = 0; g < GROUPS; ++g) {
        const int rb = (g & 1);                // read buffer (group g)
        const int wb = rb ^ 1;                 // write buffer (group g+1)
        // ---- stage-early: write group g+1's tile from pqv (reg->LDS, no wait) ----
        if (g < GROUPS - 1) {
#pragma unroll
            for (int i = 0; i < 6; ++i) {
                int e = tid + i * 256;
                if (e < TILE_N)
                    *(q4*)(tbuf + wb * TILE_BYTES + swze(e) * 8) = pqv[i];
            }
        }
        // ---- issue global prefetch for group g+2 ----
        float nld[24];
        if (g < GROUPS - 2) {
            const float* xg = xn + (g + 2) * 4 * DHW;
#pragma unroll
            for (int cg = 0; cg < 4; ++cg) {
                const float* xc = xg + cg * DHW;
#pragma unroll
                for (int i = 0; i < 6; ++i) nld[cg * 6 + i] = xc[goff[i]];
            }
        }
        short8 bn0 = bc0, bn1 = bc1;
        if (g < GROUPS - 1) {
            bn0 = *(const short8*)(bt + (nlo * 256 + (g + 1) * 32 + qm * 8));
            bn1 = *(const short8*)(bt + ((nlo + 16) * 256 + (g + 1) * 32 + qm * 8));
        }
        // ---- packed trilinear: all 4 channels per site (swizzled 8B entries) ----
        const char* tb = tbuf + rb * TILE_BYTES;
        q4 sc = *(const q4*)(tb + selfB);
        q4 vv[6];
#pragma unroll
        for (int si = 0; si < 6; ++si) {
            q4 v000 = *(const q4*)(tb + a00s[si]), v001 = *(const q4*)(tb + a00p[si]);
            q4 v010 = *(const q4*)(tb + a01s[si]), v011 = *(const q4*)(tb + a01p[si]);
            q4 v100 = *(const q4*)(tb + a10s[si]), v101 = *(const q4*)(tb + a10p[si]);
            q4 v110 = *(const q4*)(tb + a11s[si]), v111 = *(const q4*)(tb + a11p[si]);
            h2 fx = fx2[si], fy = fy2[si], fz = fz2[si];
            h2 c00l = v000.lo + fx * (v001.lo - v000.lo);
            h2 c00h = v000.hi + fx * (v001.hi - v000.hi);
            h2 c01l = v010.lo + fx * (v011.lo - v010.lo);
            h2 c01h = v010.hi + fx * (v011.hi - v010.hi);
            h2 c10l = v100.lo + fx * (v101.lo - v100.lo);
            h2 c10h = v100.hi + fx * (v101.hi - v100.hi);
            h2 c11l = v110.lo + fx * (v111.lo - v110.lo);
            h2 c11h = v110.hi + fx * (v111.hi - v110.hi);
            h2 c0l = c00l + fy * (c01l - c00l);
            h2 c0h = c00h + fy * (c01h - c00h);
            h2 c1l = c10l + fy * (c11l - c10l);
            h2 c1h = c10h + fy * (c11h - c10h);
            vv[si].lo = c0l + fz * (c1l - c0l);
            vv[si].hi = c0h + fz * (c1h - c0h);
        }
        // ---- token assembly: packed f16 math on channel pairs ----
#pragma unroll
        for (int pr = 0; pr < 2; ++pr) {
            h2 X  = pr ? sc.hi : sc.lo;
            h2 V0 = pr ? vv[0].hi : vv[0].lo;
            h2 V1 = pr ? vv[1].hi : vv[1].lo;
            h2 V2 = pr ? vv[2].hi : vv[2].lo;
            h2 V3 = pr ? vv[3].hi : vv[3].lo;
            h2 V4 = pr ? vv[4].hi : vv[4].lo;
            h2 V5 = pr ? vv[5].hi : vv[5].lo;
            h2 xv2 = X + X;
            h2 s0 = V0 + V1, dm0 = V0 - V1;
            h2 t1 = HHALF * s0;
            h2 d0 = dm0 * hir[0];
            h2 gx = d0 * hux[0], gy = d0 * huy[0], gz = d0 * huz[0];
            h2 l  = (s0 - xv2) * hq[0];
            h2 s1 = V2 + V3, dm1 = V2 - V3;
            h2 t2 = HHALF * s1;
            h2 d1 = dm1 * hir[1];
            gx = d1 * hux[1] + gx; gy = d1 * huy[1] + gy; gz = d1 * huz[1] + gz;
            l  = (s1 - xv2) * hq[1] + l;
            h2 s2v = V4 + V5, dm2 = V4 - V5;
            h2 t3 = HHALF * s2v;
            h2 d2 = dm2 * hir[2];
            gx = d2 * hux[2] + gx; gy = d2 * huy[2] + gy; gz = d2 * huz[2] + gz;
            l  = (s2v - xv2) * hq[2] + l;
            // word packing: .x channel takes lo16s, .y channel hi16s
            uint4 twa, twb;
            twa.x = __builtin_amdgcn_perm(h2u(t1), h2u(X),  0x05040100u);
            twa.y = __builtin_amdgcn_perm(h2u(t3), h2u(t2), 0x05040100u);
            twa.z = __builtin_amdgcn_perm(h2u(gy), h2u(gx), 0x05040100u);
            twa.w = __builtin_amdgcn_perm(h2u(l),  h2u(gz), 0x05040100u);
            twb.x = __builtin_amdgcn_perm(h2u(t1), h2u(X),  0x07060302u);
            twb.y = __builtin_amdgcn_perm(h2u(t3), h2u(t2), 0x07060302u);
            twb.z = __builtin_amdgcn_perm(h2u(gy), h2u(gx), 0x07060302u);
            twb.w = __builtin_amdgcn_perm(h2u(l),  h2u(gz), 0x07060302u);
            int qa = (2 * pr)     ^ tokq;
            int qb = (2 * pr + 1) ^ tokq;
            *(uint4*)(tokb + tid * TOK_STR + qa * 16) = twa;
            *(uint4*)(tokb + tid * TOK_STR + qb * 16) = twb;
        }
        // ---- MFMA: K-chunk g (k = g*32 .. g*32+31), fp16 ----
        // Tokens are wave-private: in-order per-wave LDS suffices, no barrier.
        {
            half8 hb0 = __builtin_bit_cast(half8, bc0);
            half8 hb1 = __builtin_bit_cast(half8, bc1);
#pragma unroll
            for (int mt = 0; mt < 4; ++mt) {
                int row = w64 + mt * 16 + nlo;
                int qe  = qm ^ ((row >> 3) & 3);
                half8 a = __builtin_bit_cast(half8,
                          *(const short8*)(tokb + row * TOK_STR + qe * 16));
                acc[mt][0] = __builtin_amdgcn_mfma_f32_16x16x32_f16(a, hb0, acc[mt][0], 0, 0, 0);
                acc[mt][1] = __builtin_amdgcn_mfma_f32_16x16x32_f16(a, hb1, acc[mt][1], 0, 0, 0);
            }
        }
        bc0 = bn0; bc1 = bn1;

        // ---- pack g+2's loads into pqv for next iteration's stage ----
        if (g < GROUPS - 2) {
#pragma unroll
            for (int i = 0; i < 6; ++i) {
                pqv[i].lo = pkrtz(nld[i], nld[6 + i]);
                pqv[i].hi = pkrtz(nld[12 + i], nld[18 + i]);
            }
        }
        __syncthreads();   // single rendezvous: buf[wb] staged, buf[rb] reads done
    }

    // ---- C writeback via LDS (col-swizzled, conflict-free) ----
    {
#pragma unroll
        for (int mt = 0; mt < 4; ++mt)
#pragma unroll
            for (int nt = 0; nt < 2; ++nt)
#pragma unroll
                for (int r = 0; r < 4; ++r) {
                    int vr = w64 + mt * 16 + qm * 4 + r;
                    int col = nt * 16 + nlo;
                    cbuf[vr * 36 + (col ^ (vr & 31))] = acc[mt][nt][r];
                }
    }
    __syncthreads();

    // ---- epilogue: out = x + delta + b_mix (coalesced, nontemporal) ----
    const float* dr = cbuf + tid * 36;
    float* on = out + (size_t)n * CH * DHW;
#pragma unroll
    for (int o = 0; o < 32; ++o)
        __builtin_nontemporal_store(
            xn[o * DHW + pos] + dr[o ^ (tid & 31)] + ws[WS_BM + o],
            on + o * DHW + pos);
}

extern "C" void kernel_launch(void* const* d_in, const int* in_sizes, int n_in,
                              void* d_out, int out_size, void* d_ws, size_t ws_size,
                              hipStream_t stream) {
    const float *x = (const float*)d_in[0], *w_field = (const float*)d_in[1],
                *b_field = (const float*)d_in[2], *gates = (const float*)d_in[3],
                *w_mix = (const float*)d_in[4], *b_mix = (const float*)d_in[5];
    for (int i = 0; i < n_in; ++i) {
        switch (in_sizes[i]) {
            case NB * CH * DHW: x       = (const float*)d_in[i]; break;
            case 12 * CH:       w_field = (const float*)d_in[i]; break;
            case 12:            b_field = (const float*)d_in[i]; break;
            case TT:            gates   = (const float*)d_in[i]; break;
            case CH * TT * CH:  w_mix   = (const float*)d_in[i]; break;
            case CH:            b_mix   = (const float*)d_in[i]; break;
            default: break;
        }
    }
    float* ws = (float*)d_ws;
    prep_kernel<<<32, 256, 0, stream>>>(w_field, b_field, gates, w_mix, b_mix, ws);
    geo_main<<<864, 256, 0, stream>>>(x, ws, (float*)d_out);
}